// Round 1
// baseline (606.945 us; speedup 1.0000x reference)
//
#include <hip/hip_runtime.h>

#define N_NODES 100000
#define C_DIM 128
#define E_EDGES 800000
#define V_OUT 50000
#define EN (E_EDGES + N_NODES) /* 900000 */

#define SCAN_CHUNK 1024
#define NBLK ((N_NODES + SCAN_CHUNK - 1) / SCAN_CHUNK) /* 98 */

// ---------------------------------------------------------------------------
// GEMM: h[n,c] = sum_k x[n,k] * W[c,k], fused per-node attention scores
// a_s[n] = h[n,:] . att_src, a_d[n] = h[n,:] . att_dst
// Tile: 32 nodes/block, 256 threads; thread (tc=tid&31, tn=tid>>5) computes
// nodes tn*4..tn*4+3 x cols 4tc..4tc+3 (4x4 register block).
// W staged transposed in LDS in two k-halves (keeps LDS at ~50KB -> 3 blocks/CU).
// ---------------------------------------------------------------------------
__global__ __launch_bounds__(256) void gemm_scores(
    const float* __restrict__ x, const float* __restrict__ W,
    const float* __restrict__ att_s, const float* __restrict__ att_d,
    float* __restrict__ h, float* __restrict__ a_s, float* __restrict__ a_d)
{
    __shared__ float Wt[64 * 132];   // Wt[kk*132 + c] = W[c*128 + kbase + kk]
    __shared__ float xs[32 * 128];   // xs[n*128 + k]
    const int tid = threadIdx.x;
    const int nb = blockIdx.x * 32;

    // stage x tile (32 nodes x 128 floats) via float4, fully coalesced
    #pragma unroll
    for (int i = 0; i < 4; ++i) {
        int f4 = tid + i * 256;                 // 1024 float4 total
        int n = f4 >> 5, k4 = (f4 & 31) << 2;
        *reinterpret_cast<float4*>(&xs[n * 128 + k4]) =
            *reinterpret_cast<const float4*>(&x[(long)(nb + n) * 128 + k4]);
    }

    const int tc = tid & 31;
    const int tn = tid >> 5;
    float acc[4][4] = {};

    for (int half = 0; half < 2; ++half) {
        __syncthreads();  // xs ready (half 0) / prior compute done before Wt overwrite (half 1)
        #pragma unroll
        for (int i = 0; i < 8; ++i) {
            int f4 = tid + i * 256;             // 2048 float4 = 64x128 elements
            int c = f4 >> 4, kk4 = (f4 & 15) << 2;
            float4 w = *reinterpret_cast<const float4*>(&W[c * 128 + half * 64 + kk4]);
            Wt[(kk4 + 0) * 132 + c] = w.x;
            Wt[(kk4 + 1) * 132 + c] = w.y;
            Wt[(kk4 + 2) * 132 + c] = w.z;
            Wt[(kk4 + 3) * 132 + c] = w.w;
        }
        __syncthreads();
        const int kbase = half * 64;
        #pragma unroll 8
        for (int kk = 0; kk < 64; ++kk) {
            float4 w4 = *reinterpret_cast<const float4*>(&Wt[kk * 132 + (tc << 2)]);
            #pragma unroll
            for (int i = 0; i < 4; ++i) {
                float xv = xs[(tn * 4 + i) * 128 + kbase + kk];
                acc[i][0] = fmaf(xv, w4.x, acc[i][0]);
                acc[i][1] = fmaf(xv, w4.y, acc[i][1]);
                acc[i][2] = fmaf(xv, w4.z, acc[i][2]);
                acc[i][3] = fmaf(xv, w4.w, acc[i][3]);
            }
        }
    }

    const int c0 = tc << 2;
    const float4 as4 = *reinterpret_cast<const float4*>(&att_s[c0]);
    const float4 ad4 = *reinterpret_cast<const float4*>(&att_d[c0]);
    #pragma unroll
    for (int i = 0; i < 4; ++i) {
        int n = nb + tn * 4 + i;
        float4 hv = make_float4(acc[i][0], acc[i][1], acc[i][2], acc[i][3]);
        *reinterpret_cast<float4*>(&h[(long)n * 128 + c0]) = hv;
        float ps = hv.x * as4.x + hv.y * as4.y + hv.z * as4.z + hv.w * as4.w;
        float pd = hv.x * ad4.x + hv.y * ad4.y + hv.z * ad4.z + hv.w * ad4.w;
        // reduce over the 32 tc-lanes of this half-wave (tid = tn*32 + tc)
        #pragma unroll
        for (int d = 1; d < 32; d <<= 1) {
            ps += __shfl_xor(ps, d);
            pd += __shfl_xor(pd, d);
        }
        if (tc == 0) { a_s[n] = ps; a_d[n] = pd; }
    }
}

// ---------------------------------------------------------------------------
// CSR build: histogram of destination degrees (incl. self-loops)
// ---------------------------------------------------------------------------
__global__ void hist_kernel(const int* __restrict__ edge_dst, int* __restrict__ deg)
{
    int e = blockIdx.x * 256 + threadIdx.x;
    if (e >= EN) return;
    int dst = (e < E_EDGES) ? edge_dst[e] : (e - E_EDGES);
    atomicAdd(&deg[dst], 1);
}

// per-1024-chunk block sums
__global__ __launch_bounds__(256) void scan_sums(const int* __restrict__ deg, int* __restrict__ bsums)
{
    __shared__ int sd[256];
    int tid = threadIdx.x;
    int base = blockIdx.x * SCAN_CHUNK + tid * 4;
    int s = 0;
    #pragma unroll
    for (int i = 0; i < 4; ++i) {
        int idx = base + i;
        if (idx < N_NODES) s += deg[idx];
    }
    sd[tid] = s;
    __syncthreads();
    for (int off = 128; off > 0; off >>= 1) {
        if (tid < off) sd[tid] += sd[tid + off];
        __syncthreads();
    }
    if (tid == 0) bsums[blockIdx.x] = sd[0];
}

// exclusive scan of NBLK (<=128) block sums, single block of 128 threads
__global__ void scan_mid(int* __restrict__ bsums)
{
    __shared__ int sd[128];
    int tid = threadIdx.x;
    int v = (tid < NBLK) ? bsums[tid] : 0;
    sd[tid] = v;
    __syncthreads();
    for (int off = 1; off < 128; off <<= 1) {
        int t = (tid >= off) ? sd[tid - off] : 0;
        __syncthreads();
        sd[tid] += t;
        __syncthreads();
    }
    if (tid < NBLK) bsums[tid] = sd[tid] - v;   // exclusive
}

// block-level exclusive scan + global offset; writes offs[] and pos[] cursors
__global__ __launch_bounds__(256) void scan_blocks(
    const int* __restrict__ deg, const int* __restrict__ bsums_excl,
    int* __restrict__ offs, int* __restrict__ pos)
{
    __shared__ int sd[256];
    int tid = threadIdx.x;
    int base = blockIdx.x * SCAN_CHUNK + tid * 4;
    int v[4];
    int s = 0;
    #pragma unroll
    for (int i = 0; i < 4; ++i) {
        int idx = base + i;
        v[i] = (idx < N_NODES) ? deg[idx] : 0;
        s += v[i];
    }
    sd[tid] = s;
    __syncthreads();
    for (int off = 1; off < 256; off <<= 1) {
        int t = (tid >= off) ? sd[tid - off] : 0;
        __syncthreads();
        sd[tid] += t;
        __syncthreads();
    }
    int excl = sd[tid] - s + bsums_excl[blockIdx.x];
    #pragma unroll
    for (int i = 0; i < 4; ++i) {
        int idx = base + i;
        if (idx < N_NODES) { offs[idx] = excl; pos[idx] = excl; }
        excl += v[i];
    }
    if (blockIdx.x == 0 && tid == 0) offs[N_NODES] = EN;  // total is deterministic
}

__global__ void scatter_kernel(const int* __restrict__ edges, int* __restrict__ pos,
                               int* __restrict__ esrc)
{
    int e = blockIdx.x * 256 + threadIdx.x;
    if (e >= EN) return;
    int src, dst;
    if (e < E_EDGES) { src = edges[e]; dst = edges[E_EDGES + e]; }
    else             { src = dst = e - E_EDGES; }
    int slot = atomicAdd(&pos[dst], 1);
    esrc[slot] = src;
}

// ---------------------------------------------------------------------------
// Softmax aggregation: one wave per destination node.
// Pass 1: wave-parallel max over incoming edges. Pass 2: fused unnormalized
// exp-weights + weighted h[src] accumulation (lane owns 2 channels), then
// normalize by the wave-reduced denominator and add bias. No output atomics.
// ---------------------------------------------------------------------------
__global__ __launch_bounds__(256) void aggregate(
    const float* __restrict__ h, const float* __restrict__ a_s,
    const float* __restrict__ a_d, const float* __restrict__ bias,
    const int* __restrict__ offs, const int* __restrict__ esrc,
    float* __restrict__ out)
{
    const int wave = threadIdx.x >> 6;
    const int lane = threadIdx.x & 63;
    const int node = blockIdx.x * 4 + wave;   // grid*4 == N_NODES exactly

    const int start = offs[node];
    const int end   = offs[node + 1];
    const float ad  = a_d[node];

    // pass 1: max of leaky_relu(a_s[src] + a_d[node])
    float m = -INFINITY;
    for (int j0 = start; j0 < end; j0 += 64) {
        int j = j0 + lane;
        if (j < end) {
            float e = a_s[esrc[j]] + ad;
            e = (e >= 0.0f) ? e : 0.2f * e;
            m = fmaxf(m, e);
        }
    }
    #pragma unroll
    for (int d = 1; d < 64; d <<= 1) m = fmaxf(m, __shfl_xor(m, d));

    // pass 2: unnormalized weights + accumulation
    float accx = 0.0f, accy = 0.0f;
    float dsum = 0.0f;
    for (int j0 = start; j0 < end; j0 += 64) {
        int j = j0 + lane;
        int cnt = min(64, end - j0);
        int s_l = 0;
        float w_l = 0.0f;
        if (j < end) {
            s_l = esrc[j];
            float e = a_s[s_l] + ad;
            e = (e >= 0.0f) ? e : 0.2f * e;
            w_l = expf(e - m);
            dsum += w_l;
        }
        for (int jj = 0; jj < cnt; ++jj) {
            float w = __shfl(w_l, jj);
            int s   = __shfl(s_l, jj);
            const float2 hv = *reinterpret_cast<const float2*>(h + ((long)s << 7) + (lane << 1));
            accx = fmaf(w, hv.x, accx);
            accy = fmaf(w, hv.y, accy);
        }
    }
    #pragma unroll
    for (int d = 1; d < 64; d <<= 1) dsum += __shfl_xor(dsum, d);
    float inv = 1.0f / (dsum + 1e-16f);

    int c = lane << 1;
    float2 res;
    res.x = fmaf(accx, inv, bias[c]);
    res.y = fmaf(accy, inv, bias[c + 1]);
    *reinterpret_cast<float2*>(out + ((long)node << 7) + c) = res;
}

__global__ void gather_out(const float* __restrict__ h, const int* __restrict__ idx,
                           float* __restrict__ out)
{
    int g = blockIdx.x * 256 + threadIdx.x;   // over V_OUT*32 float4s
    int v = g >> 5, c4 = (g & 31) << 2;
    long src = (long)idx[v] * C_DIM + c4;
    *reinterpret_cast<float4*>(out + ((long)v * C_DIM + c4)) =
        *reinterpret_cast<const float4*>(h + src);
}

// ---------------------------------------------------------------------------
extern "C" void kernel_launch(void* const* d_in, const int* in_sizes, int n_in,
                              void* d_out, int out_size, void* d_ws, size_t ws_size,
                              hipStream_t stream)
{
    const float* emb = (const float*)d_in[0];
    const float* W1  = (const float*)d_in[1];
    const float* as1 = (const float*)d_in[2];
    const float* ad1 = (const float*)d_in[3];
    const float* b1  = (const float*)d_in[4];
    const float* W2  = (const float*)d_in[5];
    const float* as2 = (const float*)d_in[6];
    const float* ad2 = (const float*)d_in[7];
    const float* b2  = (const float*)d_in[8];
    const int* edges1 = (const int*)d_in[9];
    const int* edges2 = (const int*)d_in[10];
    const int* idxm   = (const int*)d_in[11];
    float* out = (float*)d_out;

    char* p = (char*)d_ws;
    auto alloc = [&](size_t bytes) {
        char* r = p;
        p += (bytes + 255) & ~(size_t)255;
        return r;
    };
    float* hA  = (float*)alloc((size_t)N_NODES * C_DIM * 4);  // 51.2 MB
    float* hB  = (float*)alloc((size_t)N_NODES * C_DIM * 4);  // 51.2 MB
    float* aS  = (float*)alloc((size_t)N_NODES * 4);
    float* aD  = (float*)alloc((size_t)N_NODES * 4);
    int* deg   = (int*)alloc((size_t)N_NODES * 4);
    int* offs  = (int*)alloc((size_t)(N_NODES + 1) * 4);
    int* pos   = (int*)alloc((size_t)N_NODES * 4);
    int* esrc  = (int*)alloc((size_t)EN * 4);                 // 3.6 MB
    int* bsums = (int*)alloc(128 * 4);

    const int egrid = (EN + 255) / 256;

    // ---------------- layer 1: x = emb -> h in hA -> aggregated into hB ----
    gemm_scores<<<N_NODES / 32, 256, 0, stream>>>(emb, W1, as1, ad1, hA, aS, aD);
    hipMemsetAsync(deg, 0, (size_t)N_NODES * 4, stream);
    hist_kernel<<<egrid, 256, 0, stream>>>(edges1 + E_EDGES, deg);
    scan_sums<<<NBLK, 256, 0, stream>>>(deg, bsums);
    scan_mid<<<1, 128, 0, stream>>>(bsums);
    scan_blocks<<<NBLK, 256, 0, stream>>>(deg, bsums, offs, pos);
    scatter_kernel<<<egrid, 256, 0, stream>>>(edges1, pos, esrc);
    aggregate<<<N_NODES / 4, 256, 0, stream>>>(hA, aS, aD, b1, offs, esrc, hB);

    // ---------------- layer 2: x = hB -> h in hA -> aggregated into hB -----
    gemm_scores<<<N_NODES / 32, 256, 0, stream>>>(hB, W2, as2, ad2, hA, aS, aD);
    hipMemsetAsync(deg, 0, (size_t)N_NODES * 4, stream);
    hist_kernel<<<egrid, 256, 0, stream>>>(edges2 + E_EDGES, deg);
    scan_sums<<<NBLK, 256, 0, stream>>>(deg, bsums);
    scan_mid<<<1, 128, 0, stream>>>(bsums);
    scan_blocks<<<NBLK, 256, 0, stream>>>(deg, bsums, offs, pos);
    scatter_kernel<<<egrid, 256, 0, stream>>>(edges2, pos, esrc);
    aggregate<<<N_NODES / 4, 256, 0, stream>>>(hA, aS, aD, b2, offs, esrc, hB);

    // ---------------- final gather ----------------------------------------
    gather_out<<<(V_OUT * 32) / 256, 256, 0, stream>>>(hB, idxm, out);
}

// Round 2
// 541.622 us; speedup vs baseline: 1.1206x; 1.1206x over previous
//
#include <hip/hip_runtime.h>

#define N_NODES 100000
#define C_DIM 128
#define E_EDGES 800000
#define V_OUT 50000
#define EN (E_EDGES + N_NODES)      /* 900000  per-layer CSR entries */
#define M2 (2 * N_NODES)            /* 200000  concatenated deg/offs */
#define EN2 (2 * EN)                /* 1800000 concatenated esrc */

#define SCAN_CHUNK 1024
#define NBLK ((M2 + SCAN_CHUNK - 1) / SCAN_CHUNK) /* 196 */

typedef unsigned int uint;
typedef unsigned short ushort;
typedef __attribute__((ext_vector_type(8))) short bf16x8;
typedef __attribute__((ext_vector_type(4))) float f32x4;

static __device__ __forceinline__ ushort f2bf(float f) {
    uint u = __float_as_uint(f);
    u += 0x7fffu + ((u >> 16) & 1);   // round-to-nearest-even
    return (ushort)(u >> 16);
}

// ---------------------------------------------------------------------------
// fp32 -> bf16 bulk convert (n must be multiple of 4)
// ---------------------------------------------------------------------------
__global__ void f2bf_kernel(const float* __restrict__ in, ushort* __restrict__ out, int n4)
{
    int i = blockIdx.x * 256 + threadIdx.x;
    if (i >= n4) return;
    float4 v = reinterpret_cast<const float4*>(in)[i];
    ushort4 r;
    r.x = f2bf(v.x); r.y = f2bf(v.y); r.z = f2bf(v.z); r.w = f2bf(v.w);
    reinterpret_cast<ushort4*>(out)[i] = r;
}

// ---------------------------------------------------------------------------
// MFMA GEMM: h[n,c] = sum_k x[n,k] * W[c,k] (bf16 in, fp32 acc, bf16 out)
// + fused per-node scores a_s = h.att_src, a_d = h.att_dst (fp32, from acc).
// One wave per 16-node tile; 8 c-tiles of 16 channels; K=128 via 4 MFMA.
// A frag: A[m=lane&15][k=quad*8+j]; B frag mirrored; D: col=lane&15,
// row=quad*4+reg  (per guide, HW-verified layouts).
// ---------------------------------------------------------------------------
__global__ __launch_bounds__(256) void gemm_mfma(
    const ushort* __restrict__ xb, const ushort* __restrict__ Wb,
    const float* __restrict__ att_s, const float* __restrict__ att_d,
    ushort* __restrict__ hb, float* __restrict__ a_s, float* __restrict__ a_d)
{
    const int lane = threadIdx.x & 63;
    const int wv   = threadIdx.x >> 6;
    const int nb   = (blockIdx.x * 4 + wv) * 16;
    if (nb >= N_NODES) return;
    const int m    = lane & 15;
    const int quad = lane >> 4;

    bf16x8 a[4];
    const ushort* xrow = xb + (long)(nb + m) * 128 + quad * 8;
    #pragma unroll
    for (int ki = 0; ki < 4; ++ki)
        a[ki] = *reinterpret_cast<const bf16x8*>(xrow + ki * 32);

    float ps[4] = {0, 0, 0, 0}, pd[4] = {0, 0, 0, 0};

    #pragma unroll
    for (int ct = 0; ct < 8; ++ct) {
        const int c = ct * 16 + m;
        const ushort* wrow = Wb + (long)c * 128 + quad * 8;
        f32x4 acc = {0.f, 0.f, 0.f, 0.f};
        #pragma unroll
        for (int ki = 0; ki < 4; ++ki) {
            bf16x8 b = *reinterpret_cast<const bf16x8*>(wrow + ki * 32);
            acc = __builtin_amdgcn_mfma_f32_16x16x32_bf16(a[ki], b, acc, 0, 0, 0);
        }
        const float asc = att_s[c], adc = att_d[c];
        #pragma unroll
        for (int r = 0; r < 4; ++r) {
            const int node = nb + quad * 4 + r;
            hb[(long)node * 128 + c] = f2bf(acc[r]);
            ps[r] = fmaf(acc[r], asc, ps[r]);
            pd[r] = fmaf(acc[r], adc, pd[r]);
        }
    }
    #pragma unroll
    for (int r = 0; r < 4; ++r) {
        float s = ps[r], d = pd[r];
        #pragma unroll
        for (int x = 1; x < 16; x <<= 1) { s += __shfl_xor(s, x); d += __shfl_xor(d, x); }
        if (m == 0) {
            const int node = nb + quad * 4 + r;
            a_s[node] = s; a_d[node] = d;
        }
    }
}

// ---------------------------------------------------------------------------
// Combined CSR build for BOTH layers: deg/offs over 2N concatenated nodes,
// esrc over 2*EN slots. Self-loops appended after the E real edges.
// ---------------------------------------------------------------------------
__global__ void hist2_kernel(const int* __restrict__ e1, const int* __restrict__ e2,
                             int* __restrict__ deg)
{
    int e = blockIdx.x * 256 + threadIdx.x;
    if (e >= EN2) return;
    int dst, base;
    if (e < EN) { dst = (e < E_EDGES) ? e1[E_EDGES + e] : (e - E_EDGES); base = 0; }
    else { int f = e - EN; dst = (f < E_EDGES) ? e2[E_EDGES + f] : (f - E_EDGES); base = N_NODES; }
    atomicAdd(&deg[base + dst], 1);
}

__global__ __launch_bounds__(256) void scan_sums(const int* __restrict__ deg, int* __restrict__ bsums)
{
    __shared__ int sd[256];
    int tid = threadIdx.x;
    int base = blockIdx.x * SCAN_CHUNK + tid * 4;
    int s = 0;
    #pragma unroll
    for (int i = 0; i < 4; ++i) { int idx = base + i; if (idx < M2) s += deg[idx]; }
    sd[tid] = s;
    __syncthreads();
    for (int off = 128; off > 0; off >>= 1) {
        if (tid < off) sd[tid] += sd[tid + off];
        __syncthreads();
    }
    if (tid == 0) bsums[blockIdx.x] = sd[0];
}

__global__ void scan_mid(int* __restrict__ bsums)
{
    __shared__ int sd[256];
    int tid = threadIdx.x;
    int v = (tid < NBLK) ? bsums[tid] : 0;
    sd[tid] = v;
    __syncthreads();
    for (int off = 1; off < 256; off <<= 1) {
        int t = (tid >= off) ? sd[tid - off] : 0;
        __syncthreads();
        sd[tid] += t;
        __syncthreads();
    }
    if (tid < NBLK) bsums[tid] = sd[tid] - v;   // exclusive
}

__global__ __launch_bounds__(256) void scan_blocks(
    const int* __restrict__ deg, const int* __restrict__ bsums_excl,
    int* __restrict__ offs, int* __restrict__ pos)
{
    __shared__ int sd[256];
    int tid = threadIdx.x;
    int base = blockIdx.x * SCAN_CHUNK + tid * 4;
    int v[4];
    int s = 0;
    #pragma unroll
    for (int i = 0; i < 4; ++i) {
        int idx = base + i;
        v[i] = (idx < M2) ? deg[idx] : 0;
        s += v[i];
    }
    sd[tid] = s;
    __syncthreads();
    for (int off = 1; off < 256; off <<= 1) {
        int t = (tid >= off) ? sd[tid - off] : 0;
        __syncthreads();
        sd[tid] += t;
        __syncthreads();
    }
    int excl = sd[tid] - s + bsums_excl[blockIdx.x];
    #pragma unroll
    for (int i = 0; i < 4; ++i) {
        int idx = base + i;
        if (idx < M2) { offs[idx] = excl; pos[idx] = excl; }
        excl += v[i];
    }
    if (blockIdx.x == 0 && tid == 0) offs[M2] = EN2;  // total is deterministic
}

__global__ void scatter2_kernel(const int* __restrict__ e1, const int* __restrict__ e2,
                                int* __restrict__ pos, int* __restrict__ esrc)
{
    int e = blockIdx.x * 256 + threadIdx.x;
    if (e >= EN2) return;
    int src, dst, base;
    if (e < EN) {
        if (e < E_EDGES) { src = e1[e]; dst = e1[E_EDGES + e]; }
        else             { src = dst = e - E_EDGES; }
        base = 0;
    } else {
        int f = e - EN;
        if (f < E_EDGES) { src = e2[f]; dst = e2[E_EDGES + f]; }
        else             { src = dst = f - E_EDGES; }
        base = N_NODES;
    }
    int slot = atomicAdd(&pos[base + dst], 1);
    esrc[slot] = src;
}

// ---------------------------------------------------------------------------
// Softmax aggregation, one wave per destination node, single pass.
// No segment-max pass: scores are O(10), exp() is safe in fp32 and softmax is
// shift-invariant, so results match the reference to rounding. Lane owns 2
// channels (bf16 pair = 4B coalesced gather of h[src]). fp32 accumulate.
// WRITE_BF16=1 -> packed bf16 out (feeds next layer's MFMA gemm);
// WRITE_BF16=0 -> fp32 out (feeds final gather).
// ---------------------------------------------------------------------------
template <int WRITE_BF16>
__global__ __launch_bounds__(256) void aggregate(
    const ushort* __restrict__ hb, const float* __restrict__ a_s,
    const float* __restrict__ a_d, const float* __restrict__ bias,
    const int* __restrict__ offs, const int* __restrict__ esrc,
    void* __restrict__ outp, int obase)
{
    const int wave = threadIdx.x >> 6;
    const int lane = threadIdx.x & 63;
    const int node = blockIdx.x * 4 + wave;   // grid*4 == N_NODES exactly

    const int start = offs[obase + node];
    const int end   = offs[obase + node + 1];
    const float ad  = a_d[node];

    float accx = 0.0f, accy = 0.0f, dsum = 0.0f;
    for (int j0 = start; j0 < end; j0 += 64) {
        int j = j0 + lane;
        int cnt = min(64, end - j0);
        int s_l = 0;
        float w_l = 0.0f;
        if (j < end) {
            s_l = esrc[j];
            float e = a_s[s_l] + ad;
            e = (e >= 0.0f) ? e : 0.2f * e;
            w_l = __expf(e);
            dsum += w_l;
        }
        for (int jj = 0; jj < cnt; ++jj) {
            float w = __shfl(w_l, jj);
            int s   = __shfl(s_l, jj);
            uint hv = *reinterpret_cast<const uint*>(hb + ((long)s << 7) + (lane << 1));
            float hx = __uint_as_float(hv << 16);
            float hy = __uint_as_float(hv & 0xffff0000u);
            accx = fmaf(w, hx, accx);
            accy = fmaf(w, hy, accy);
        }
    }
    #pragma unroll
    for (int d = 1; d < 64; d <<= 1) dsum += __shfl_xor(dsum, d);
    const float inv = 1.0f / (dsum + 1e-16f);

    const int c = lane << 1;
    const float rx = fmaf(accx, inv, bias[c]);
    const float ry = fmaf(accy, inv, bias[c + 1]);
    if (WRITE_BF16) {
        uint pk = (uint)f2bf(rx) | ((uint)f2bf(ry) << 16);
        reinterpret_cast<uint*>(outp)[((long)node << 6) + lane] = pk;
    } else {
        float2 r; r.x = rx; r.y = ry;
        reinterpret_cast<float2*>(outp)[((long)node << 6) + lane] = r;
    }
}

__global__ void gather_out(const float* __restrict__ h, const int* __restrict__ idx,
                           float* __restrict__ out)
{
    int g = blockIdx.x * 256 + threadIdx.x;   // over V_OUT*32 float4s
    int v = g >> 5, c4 = (g & 31) << 2;
    long src = (long)idx[v] * C_DIM + c4;
    *reinterpret_cast<float4*>(out + ((long)v * C_DIM + c4)) =
        *reinterpret_cast<const float4*>(h + src);
}

// ---------------------------------------------------------------------------
extern "C" void kernel_launch(void* const* d_in, const int* in_sizes, int n_in,
                              void* d_out, int out_size, void* d_ws, size_t ws_size,
                              hipStream_t stream)
{
    const float* emb = (const float*)d_in[0];
    const float* W1  = (const float*)d_in[1];
    const float* as1 = (const float*)d_in[2];
    const float* ad1 = (const float*)d_in[3];
    const float* b1  = (const float*)d_in[4];
    const float* W2  = (const float*)d_in[5];
    const float* as2 = (const float*)d_in[6];
    const float* ad2 = (const float*)d_in[7];
    const float* b2  = (const float*)d_in[8];
    const int* edges1 = (const int*)d_in[9];
    const int* edges2 = (const int*)d_in[10];
    const int* idxm   = (const int*)d_in[11];
    float* out = (float*)d_out;

    char* p = (char*)d_ws;
    auto alloc = [&](size_t bytes) {
        char* r = p;
        p += (bytes + 255) & ~(size_t)255;
        return r;
    };
    // hB (fp32 layer-2 output, 51.2 MB) time-shares its first half with xb
    // (bf16 emb, 25.6 MB): xb dies after gemm1, hB is born at aggregate-2.
    float*  hB   = (float*)alloc((size_t)N_NODES * C_DIM * 4);
    ushort* xb   = (ushort*)hB;
    ushort* hb   = (ushort*)alloc((size_t)N_NODES * C_DIM * 2);  // gemm out (both layers)
    ushort* a1o  = (ushort*)alloc((size_t)N_NODES * C_DIM * 2);  // layer-1 agg out
    ushort* W1b  = (ushort*)alloc((size_t)C_DIM * C_DIM * 2);
    ushort* W2b  = (ushort*)alloc((size_t)C_DIM * C_DIM * 2);
    float*  aS   = (float*)alloc((size_t)N_NODES * 4);
    float*  aD   = (float*)alloc((size_t)N_NODES * 4);
    int* deg   = (int*)alloc((size_t)M2 * 4);
    int* offs  = (int*)alloc((size_t)(M2 + 1) * 4);
    int* pos   = (int*)alloc((size_t)M2 * 4);
    int* esrc  = (int*)alloc((size_t)EN2 * 4);
    int* bsums = (int*)alloc(256 * 4);

    const int egrid2 = (EN2 + 255) / 256;

    // ---- converts (independent of CSR) -----------------------------------
    f2bf_kernel<<<(N_NODES * C_DIM / 4 + 255) / 256, 256, 0, stream>>>(emb, xb, N_NODES * C_DIM / 4);
    f2bf_kernel<<<(C_DIM * C_DIM / 4 + 255) / 256, 256, 0, stream>>>(W1, W1b, C_DIM * C_DIM / 4);
    f2bf_kernel<<<(C_DIM * C_DIM / 4 + 255) / 256, 256, 0, stream>>>(W2, W2b, C_DIM * C_DIM / 4);

    // ---- combined CSR build for both layers ------------------------------
    hipMemsetAsync(deg, 0, (size_t)M2 * 4, stream);
    hist2_kernel<<<egrid2, 256, 0, stream>>>(edges1, edges2, deg);
    scan_sums<<<NBLK, 256, 0, stream>>>(deg, bsums);
    scan_mid<<<1, 256, 0, stream>>>(bsums);
    scan_blocks<<<NBLK, 256, 0, stream>>>(deg, bsums, offs, pos);
    scatter2_kernel<<<egrid2, 256, 0, stream>>>(edges1, edges2, pos, esrc);

    // ---- layer 1 ---------------------------------------------------------
    gemm_mfma<<<(N_NODES / 16 + 3) / 4, 256, 0, stream>>>(xb, W1b, as1, ad1, hb, aS, aD);
    aggregate<1><<<N_NODES / 4, 256, 0, stream>>>(hb, aS, aD, b1, offs, esrc, a1o, 0);

    // ---- layer 2 ---------------------------------------------------------
    gemm_mfma<<<(N_NODES / 16 + 3) / 4, 256, 0, stream>>>(a1o, W2b, as2, ad2, hb, aS, aD);
    aggregate<0><<<N_NODES / 4, 256, 0, stream>>>(hb, aS, aD, b2, offs, esrc, hB, N_NODES);

    // ---- final gather ----------------------------------------------------
    gather_out<<<(V_OUT * 32) / 256, 256, 0, stream>>>(hB, idxm, out);
}

// Round 3
// 380.241 us; speedup vs baseline: 1.5962x; 1.4244x over previous
//
#include <hip/hip_runtime.h>

#define N_NODES 100000
#define C_DIM 128
#define E_EDGES 800000
#define V_OUT 50000
#define EN (E_EDGES + N_NODES)      /* 900000  per-layer CSR entries */
#define M2 (2 * N_NODES)
#define EN2 (2 * EN)                /* 1800000 */

#define BSHIFT 9                    /* 512 nodes per coarse bucket */
#define NBUCK_L ((N_NODES + 511) >> 9)   /* 196 per layer */
#define NBUCK2 (2 * NBUCK_L)             /* 392 */
#define CAP 8192                    /* slab capacity; avg fill ~4608, sd ~66 */
#define P1_CHUNK 4096
#define P1_PER_T (P1_CHUNK / 256)   /* 16 */
#define NCHUNK ((EN2 + P1_CHUNK - 1) / P1_CHUNK) /* 440 */

typedef unsigned int uint;
typedef unsigned short ushort;
typedef __attribute__((ext_vector_type(8))) short bf16x8;
typedef __attribute__((ext_vector_type(4))) float f32x4;

static __device__ __forceinline__ ushort f2bf(float f) {
    uint u = __float_as_uint(f);
    u += 0x7fffu + ((u >> 16) & 1);   // round-to-nearest-even
    return (ushort)(u >> 16);
}

// ---------------------------------------------------------------------------
// fp32 -> bf16 bulk convert (weights only now)
// ---------------------------------------------------------------------------
__global__ void f2bf_kernel(const float* __restrict__ in, ushort* __restrict__ out, int n4)
{
    int i = blockIdx.x * 256 + threadIdx.x;
    if (i >= n4) return;
    float4 v = reinterpret_cast<const float4*>(in)[i];
    ushort4 r;
    r.x = f2bf(v.x); r.y = f2bf(v.y); r.z = f2bf(v.z); r.w = f2bf(v.w);
    reinterpret_cast<ushort4*>(out)[i] = r;
}

// ---------------------------------------------------------------------------
// MFMA GEMM: h[n,c] = sum_k x[n,k] * W[c,k] (bf16/fp32 in, fp32 acc, bf16 out)
// + fused scores a_s = h.att_src, a_d = h.att_dst.
// A frag: A[m=lane&15][k=quad*8+j]; B mirrored; D: col=lane&15, row=quad*4+r.
// ---------------------------------------------------------------------------
template <int IN_F32>
__global__ __launch_bounds__(256) void gemm_mfma(
    const void* __restrict__ xin, const ushort* __restrict__ Wb,
    const float* __restrict__ att_s, const float* __restrict__ att_d,
    ushort* __restrict__ hb, float* __restrict__ a_s, float* __restrict__ a_d)
{
    const int lane = threadIdx.x & 63;
    const int wv   = threadIdx.x >> 6;
    const int nb   = (blockIdx.x * 4 + wv) * 16;
    if (nb >= N_NODES) return;
    const int m    = lane & 15;
    const int quad = lane >> 4;

    bf16x8 a[4];
    if (IN_F32) {
        const float* xrow = (const float*)xin + (long)(nb + m) * 128 + quad * 8;
        #pragma unroll
        for (int ki = 0; ki < 4; ++ki) {
            float4 u = *reinterpret_cast<const float4*>(xrow + ki * 32);
            float4 v = *reinterpret_cast<const float4*>(xrow + ki * 32 + 4);
            bf16x8 t;
            t[0] = (short)f2bf(u.x); t[1] = (short)f2bf(u.y);
            t[2] = (short)f2bf(u.z); t[3] = (short)f2bf(u.w);
            t[4] = (short)f2bf(v.x); t[5] = (short)f2bf(v.y);
            t[6] = (short)f2bf(v.z); t[7] = (short)f2bf(v.w);
            a[ki] = t;
        }
    } else {
        const ushort* xrow = (const ushort*)xin + (long)(nb + m) * 128 + quad * 8;
        #pragma unroll
        for (int ki = 0; ki < 4; ++ki)
            a[ki] = *reinterpret_cast<const bf16x8*>(xrow + ki * 32);
    }

    float ps[4] = {0, 0, 0, 0}, pd[4] = {0, 0, 0, 0};

    #pragma unroll
    for (int ct = 0; ct < 8; ++ct) {
        const int c = ct * 16 + m;
        const ushort* wrow = Wb + (long)c * 128 + quad * 8;
        f32x4 acc = {0.f, 0.f, 0.f, 0.f};
        #pragma unroll
        for (int ki = 0; ki < 4; ++ki) {
            bf16x8 b = *reinterpret_cast<const bf16x8*>(wrow + ki * 32);
            acc = __builtin_amdgcn_mfma_f32_16x16x32_bf16(a[ki], b, acc, 0, 0, 0);
        }
        const float asc = att_s[c], adc = att_d[c];
        #pragma unroll
        for (int r = 0; r < 4; ++r) {
            const int node = nb + quad * 4 + r;
            hb[(long)node * 128 + c] = f2bf(acc[r]);
            ps[r] = fmaf(acc[r], asc, ps[r]);
            pd[r] = fmaf(acc[r], adc, pd[r]);
        }
    }
    #pragma unroll
    for (int r = 0; r < 4; ++r) {
        float s = ps[r], d = pd[r];
        #pragma unroll
        for (int x = 1; x < 16; x <<= 1) { s += __shfl_xor(s, x); d += __shfl_xor(d, x); }
        if (m == 0) {
            const int node = nb + quad * 4 + r;
            a_s[node] = s; a_d[node] = d;
        }
    }
}

// ---------------------------------------------------------------------------
// CSR build, pass 1: partition edges (both layers + self-loops) into 392
// coarse buckets of 512 dst-nodes. LDS-staged ranks -> writes are coalesced
// runs into fixed-capacity slabs (packed entry: src | dst_local<<17).
// ---------------------------------------------------------------------------
__global__ __launch_bounds__(256) void partition_kernel(
    const int* __restrict__ e1, const int* __restrict__ e2,
    int* __restrict__ cursor, uint* __restrict__ slab)
{
    __shared__ int cnt[NBUCK2];
    __shared__ int basearr[NBUCK2];
    const int tid = threadIdx.x;
    for (int i = tid; i < NBUCK2; i += 256) cnt[i] = 0;
    __syncthreads();

    const int e0 = blockIdx.x * P1_CHUNK;
    uint ent[P1_PER_T];
    int  bkt[P1_PER_T];
    #pragma unroll
    for (int i = 0; i < P1_PER_T; ++i) {
        int e = e0 + i * 256 + tid;
        bkt[i] = -1;
        if (e < EN2) {
            int src, dst, lb;
            if (e < EN) {
                if (e < E_EDGES) { src = e1[e]; dst = e1[E_EDGES + e]; }
                else             { src = dst = e - E_EDGES; }
                lb = 0;
            } else {
                int f = e - EN;
                if (f < E_EDGES) { src = e2[f]; dst = e2[E_EDGES + f]; }
                else             { src = dst = f - E_EDGES; }
                lb = NBUCK_L;
            }
            bkt[i] = lb + (dst >> BSHIFT);
            ent[i] = (uint)src | ((uint)(dst & 511) << 17);
            atomicAdd(&cnt[bkt[i]], 1);
        }
    }
    __syncthreads();
    for (int b = tid; b < NBUCK2; b += 256) {
        int c = cnt[b];
        basearr[b] = (c > 0) ? atomicAdd(&cursor[b], c) : 0;
        cnt[b] = 0;                       // reuse as rank counter
    }
    __syncthreads();
    #pragma unroll
    for (int i = 0; i < P1_PER_T; ++i) {
        if (bkt[i] >= 0) {
            int r = basearr[bkt[i]] + atomicAdd(&cnt[bkt[i]], 1);
            if (r < CAP) slab[(long)bkt[i] * CAP + r] = ent[i];
        }
    }
}

// exclusive scan of the 392 bucket counts; single wave
__global__ void bucket_scan(const int* __restrict__ cursor, int* __restrict__ bbase)
{
    const int lane = threadIdx.x;     // 64 threads
    int v[7]; int s = 0;
    #pragma unroll
    for (int i = 0; i < 7; ++i) {
        int idx = lane * 7 + i;
        v[i] = (idx < NBUCK2) ? cursor[idx] : 0;
        s += v[i];
    }
    int incl = s;
    #pragma unroll
    for (int d = 1; d < 64; d <<= 1) {
        int t = __shfl_up(incl, d);
        if (lane >= d) incl += t;
    }
    int excl = incl - s;
    #pragma unroll
    for (int i = 0; i < 7; ++i) {
        int idx = lane * 7 + i;
        if (idx < NBUCK2) bbase[idx] = excl;
        excl += v[i];
    }
}

// ---------------------------------------------------------------------------
// CSR build, pass 2: one workgroup per bucket. Slab -> LDS; per-node deg +
// exclusive scan in LDS; offs written coalesced; esrc scattered only within
// this workgroup's private window (no cross-XCD line sharing).
// ---------------------------------------------------------------------------
__global__ __launch_bounds__(256) void local_csr(
    const uint* __restrict__ slab, const int* __restrict__ cursor,
    const int* __restrict__ bbase, int* __restrict__ offs, int* __restrict__ esrc)
{
    __shared__ uint ent[CAP];         // 32 KB
    __shared__ int deg[512];
    __shared__ int excl[512];
    const int b = blockIdx.x;
    const int tid = threadIdx.x;
    const int cnt = min(cursor[b], CAP);
    const int base = bbase[b];
    const int layer = (b >= NBUCK_L);
    const int node0 = (b - layer * NBUCK_L) << BSHIFT;
    const int obase = layer * N_NODES;
    const int nodes_n = min(512, N_NODES - node0);

    for (int i = tid; i < 512; i += 256) deg[i] = 0;
    __syncthreads();
    for (int i = tid; i < cnt; i += 256) {
        uint v = slab[(long)b * CAP + i];
        ent[i] = v;
        atomicAdd(&deg[v >> 17], 1);
    }
    __syncthreads();
    if (tid < 64) {                   // wave-0 scan of deg[512], 8 per lane
        int v8[8]; int s = 0;
        #pragma unroll
        for (int i = 0; i < 8; ++i) { v8[i] = deg[tid * 8 + i]; s += v8[i]; }
        int incl = s;
        #pragma unroll
        for (int d = 1; d < 64; d <<= 1) {
            int t = __shfl_up(incl, d);
            if (tid >= d) incl += t;
        }
        int e = incl - s;
        #pragma unroll
        for (int i = 0; i < 8; ++i) { excl[tid * 8 + i] = e; e += v8[i]; }
    }
    __syncthreads();
    for (int i = tid; i < nodes_n; i += 256)
        offs[obase + node0 + i] = base + excl[i];
    for (int i = tid; i < 512; i += 256) deg[i] = 0;   // reuse as rank ctr
    if (tid == 0 && node0 + 512 >= N_NODES)
        offs[obase + N_NODES] = base + cnt;            // layer sentinel
    __syncthreads();
    for (int i = tid; i < cnt; i += 256) {
        uint v = ent[i];
        int dl = v >> 17;
        int r = atomicAdd(&deg[dl], 1);
        esrc[base + excl[dl] + r] = (int)(v & 0x1ffff);
    }
}

// ---------------------------------------------------------------------------
// Softmax aggregation, one wave per destination node (see R2 notes).
// ---------------------------------------------------------------------------
template <int WRITE_BF16>
__global__ __launch_bounds__(256) void aggregate(
    const ushort* __restrict__ hb, const float* __restrict__ a_s,
    const float* __restrict__ a_d, const float* __restrict__ bias,
    const int* __restrict__ offs, const int* __restrict__ esrc,
    void* __restrict__ outp, int obase)
{
    const int wave = threadIdx.x >> 6;
    const int lane = threadIdx.x & 63;
    const int node = blockIdx.x * 4 + wave;   // grid*4 == N_NODES exactly

    const int start = offs[obase + node];
    const int end   = offs[obase + node + 1];
    const float ad  = a_d[node];

    float accx = 0.0f, accy = 0.0f, dsum = 0.0f;
    for (int j0 = start; j0 < end; j0 += 64) {
        int j = j0 + lane;
        int cnt = min(64, end - j0);
        int s_l = 0;
        float w_l = 0.0f;
        if (j < end) {
            s_l = esrc[j];
            float e = a_s[s_l] + ad;
            e = (e >= 0.0f) ? e : 0.2f * e;
            w_l = __expf(e);
            dsum += w_l;
        }
        for (int jj = 0; jj < cnt; ++jj) {
            float w = __shfl(w_l, jj);
            int s   = __shfl(s_l, jj);
            uint hv = *reinterpret_cast<const uint*>(hb + ((long)s << 7) + (lane << 1));
            float hx = __uint_as_float(hv << 16);
            float hy = __uint_as_float(hv & 0xffff0000u);
            accx = fmaf(w, hx, accx);
            accy = fmaf(w, hy, accy);
        }
    }
    #pragma unroll
    for (int d = 1; d < 64; d <<= 1) dsum += __shfl_xor(dsum, d);
    const float inv = 1.0f / (dsum + 1e-16f);

    const int c = lane << 1;
    const float rx = fmaf(accx, inv, bias[c]);
    const float ry = fmaf(accy, inv, bias[c + 1]);
    if (WRITE_BF16) {
        uint pk = (uint)f2bf(rx) | ((uint)f2bf(ry) << 16);
        reinterpret_cast<uint*>(outp)[((long)node << 6) + lane] = pk;
    } else {
        float2 r; r.x = rx; r.y = ry;
        reinterpret_cast<float2*>(outp)[((long)node << 6) + lane] = r;
    }
}

__global__ void gather_out(const float* __restrict__ h, const int* __restrict__ idx,
                           float* __restrict__ out)
{
    int g = blockIdx.x * 256 + threadIdx.x;   // over V_OUT*32 float4s
    int v = g >> 5, c4 = (g & 31) << 2;
    long src = (long)idx[v] * C_DIM + c4;
    *reinterpret_cast<float4*>(out + ((long)v * C_DIM + c4)) =
        *reinterpret_cast<const float4*>(h + src);
}

// ---------------------------------------------------------------------------
extern "C" void kernel_launch(void* const* d_in, const int* in_sizes, int n_in,
                              void* d_out, int out_size, void* d_ws, size_t ws_size,
                              hipStream_t stream)
{
    const float* emb = (const float*)d_in[0];
    const float* W1  = (const float*)d_in[1];
    const float* as1 = (const float*)d_in[2];
    const float* ad1 = (const float*)d_in[3];
    const float* b1  = (const float*)d_in[4];
    const float* W2  = (const float*)d_in[5];
    const float* as2 = (const float*)d_in[6];
    const float* ad2 = (const float*)d_in[7];
    const float* b2  = (const float*)d_in[8];
    const int* edges1 = (const int*)d_in[9];
    const int* edges2 = (const int*)d_in[10];
    const int* idxm   = (const int*)d_in[11];
    float* out = (float*)d_out;

    char* p = (char*)d_ws;
    auto alloc = [&](size_t bytes) {
        char* r = p;
        p += (bytes + 255) & ~(size_t)255;
        return r;
    };
    float*  hB   = (float*)alloc((size_t)N_NODES * C_DIM * 4);   // 51.2 MB
    ushort* hb   = (ushort*)alloc((size_t)N_NODES * C_DIM * 2);  // 25.6 MB
    ushort* a1o  = (ushort*)alloc((size_t)N_NODES * C_DIM * 2);  // 25.6 MB
    uint*   slab = (uint*)alloc((size_t)NBUCK2 * CAP * 4);       // 12.9 MB
    int*    esrc = (int*)alloc((size_t)EN2 * 4);                 // 7.2 MB
    int*    offs = (int*)alloc((size_t)(M2 + 1) * 4);
    ushort* W1b  = (ushort*)alloc((size_t)C_DIM * C_DIM * 2);
    ushort* W2b  = (ushort*)alloc((size_t)C_DIM * C_DIM * 2);
    float*  aS   = (float*)alloc((size_t)N_NODES * 4);
    float*  aD   = (float*)alloc((size_t)N_NODES * 4);
    int*  cursor = (int*)alloc((size_t)NBUCK2 * 4);
    int*  bbase  = (int*)alloc((size_t)NBUCK2 * 4);

    // ---- weight converts -------------------------------------------------
    f2bf_kernel<<<(C_DIM * C_DIM / 4 + 255) / 256, 256, 0, stream>>>(W1, W1b, C_DIM * C_DIM / 4);
    f2bf_kernel<<<(C_DIM * C_DIM / 4 + 255) / 256, 256, 0, stream>>>(W2, W2b, C_DIM * C_DIM / 4);

    // ---- CSR build (both layers) -----------------------------------------
    hipMemsetAsync(cursor, 0, (size_t)NBUCK2 * 4, stream);
    partition_kernel<<<NCHUNK, 256, 0, stream>>>(edges1, edges2, cursor, slab);
    bucket_scan<<<1, 64, 0, stream>>>(cursor, bbase);
    local_csr<<<NBUCK2, 256, 0, stream>>>(slab, cursor, bbase, offs, esrc);

    // ---- layer 1 (fp32 emb read fused into gemm) -------------------------
    gemm_mfma<1><<<(N_NODES / 16 + 3) / 4, 256, 0, stream>>>(emb, W1b, as1, ad1, hb, aS, aD);
    aggregate<1><<<N_NODES / 4, 256, 0, stream>>>(hb, aS, aD, b1, offs, esrc, a1o, 0);

    // ---- layer 2 ---------------------------------------------------------
    gemm_mfma<0><<<(N_NODES / 16 + 3) / 4, 256, 0, stream>>>(a1o, W2b, as2, ad2, hb, aS, aD);
    aggregate<0><<<N_NODES / 4, 256, 0, stream>>>(hb, aS, aD, b2, offs, esrc, hB, N_NODES);

    // ---- final gather ----------------------------------------------------
    gather_out<<<(V_OUT * 32) / 256, 256, 0, stream>>>(hB, idxm, out);
}

// Round 4
// 312.378 us; speedup vs baseline: 1.9430x; 1.2172x over previous
//
#include <hip/hip_runtime.h>

#define N_NODES 100000
#define C_DIM 128
#define E_EDGES 800000
#define V_OUT 50000
#define EN (E_EDGES + N_NODES)      /* 900000  per-layer CSR entries */
#define M2 (2 * N_NODES)
#define EN2 (2 * EN)                /* 1800000 */

#define BSHIFT 9                    /* 512 nodes per coarse bucket */
#define NBUCK_L ((N_NODES + 511) >> 9)   /* 196 per layer */
#define NBUCK2 (2 * NBUCK_L)             /* 392 */
#define CAP 8192                    /* slab capacity; avg fill ~4608 */
#define P1_CHUNK 4096
#define P1_PER_T (P1_CHUNK / 256)   /* 16 */
#define NCHUNK ((EN2 + P1_CHUNK - 1) / P1_CHUNK) /* 440 */

typedef unsigned int uint;
typedef unsigned short ushort;
typedef __attribute__((ext_vector_type(8))) short bf16x8;
typedef __attribute__((ext_vector_type(4))) float f32x4;

static __device__ __forceinline__ ushort f2bf(float f) {
    uint u = __float_as_uint(f);
    u += 0x7fffu + ((u >> 16) & 1);   // round-to-nearest-even
    return (ushort)(u >> 16);
}

// ---------------------------------------------------------------------------
// fp32 -> bf16 bulk convert (weights only)
// ---------------------------------------------------------------------------
__global__ void f2bf_kernel(const float* __restrict__ in, ushort* __restrict__ out, int n4)
{
    int i = blockIdx.x * 256 + threadIdx.x;
    if (i >= n4) return;
    float4 v = reinterpret_cast<const float4*>(in)[i];
    ushort4 r;
    r.x = f2bf(v.x); r.y = f2bf(v.y); r.z = f2bf(v.z); r.w = f2bf(v.w);
    reinterpret_cast<ushort4*>(out)[i] = r;
}

// mark nodes that appear in idx_mapping (races benign: all write 1)
__global__ void vflag_kernel(const int* __restrict__ idx, int* __restrict__ vflag)
{
    int v = blockIdx.x * 256 + threadIdx.x;
    if (v < V_OUT) vflag[idx[v]] = 1;
}

// ---------------------------------------------------------------------------
// MFMA GEMM: h[n,c] = sum_k x[n,k] * W[c,k] (bf16/fp32 in, fp32 acc, bf16 out)
// + fused scores a_s = h.att_src, a_d = h.att_dst.
// A frag: A[m=lane&15][k=quad*8+j]; B mirrored; D: col=lane&15, row=quad*4+r.
// ---------------------------------------------------------------------------
template <int IN_F32>
__global__ __launch_bounds__(256) void gemm_mfma(
    const void* __restrict__ xin, const ushort* __restrict__ Wb,
    const float* __restrict__ att_s, const float* __restrict__ att_d,
    ushort* __restrict__ hb, float* __restrict__ a_s, float* __restrict__ a_d)
{
    const int lane = threadIdx.x & 63;
    const int wv   = threadIdx.x >> 6;
    const int nb   = (blockIdx.x * 4 + wv) * 16;
    if (nb >= N_NODES) return;
    const int m    = lane & 15;
    const int quad = lane >> 4;

    bf16x8 a[4];
    if (IN_F32) {
        const float* xrow = (const float*)xin + (long)(nb + m) * 128 + quad * 8;
        #pragma unroll
        for (int ki = 0; ki < 4; ++ki) {
            float4 u = *reinterpret_cast<const float4*>(xrow + ki * 32);
            float4 v = *reinterpret_cast<const float4*>(xrow + ki * 32 + 4);
            bf16x8 t;
            t[0] = (short)f2bf(u.x); t[1] = (short)f2bf(u.y);
            t[2] = (short)f2bf(u.z); t[3] = (short)f2bf(u.w);
            t[4] = (short)f2bf(v.x); t[5] = (short)f2bf(v.y);
            t[6] = (short)f2bf(v.z); t[7] = (short)f2bf(v.w);
            a[ki] = t;
        }
    } else {
        const ushort* xrow = (const ushort*)xin + (long)(nb + m) * 128 + quad * 8;
        #pragma unroll
        for (int ki = 0; ki < 4; ++ki)
            a[ki] = *reinterpret_cast<const bf16x8*>(xrow + ki * 32);
    }

    float ps[4] = {0, 0, 0, 0}, pd[4] = {0, 0, 0, 0};

    #pragma unroll
    for (int ct = 0; ct < 8; ++ct) {
        const int c = ct * 16 + m;
        const ushort* wrow = Wb + (long)c * 128 + quad * 8;
        f32x4 acc = {0.f, 0.f, 0.f, 0.f};
        #pragma unroll
        for (int ki = 0; ki < 4; ++ki) {
            bf16x8 b = *reinterpret_cast<const bf16x8*>(wrow + ki * 32);
            acc = __builtin_amdgcn_mfma_f32_16x16x32_bf16(a[ki], b, acc, 0, 0, 0);
        }
        const float asc = att_s[c], adc = att_d[c];
        #pragma unroll
        for (int r = 0; r < 4; ++r) {
            const int node = nb + quad * 4 + r;
            hb[(long)node * 128 + c] = f2bf(acc[r]);
            ps[r] = fmaf(acc[r], asc, ps[r]);
            pd[r] = fmaf(acc[r], adc, pd[r]);
        }
    }
    #pragma unroll
    for (int r = 0; r < 4; ++r) {
        float s = ps[r], d = pd[r];
        #pragma unroll
        for (int x = 1; x < 16; x <<= 1) { s += __shfl_xor(s, x); d += __shfl_xor(d, x); }
        if (m == 0) {
            const int node = nb + quad * 4 + r;
            a_s[node] = s; a_d[node] = d;
        }
    }
}

// ---------------------------------------------------------------------------
// CSR build, pass 1: partition edges into 392 coarse buckets of 512 dst.
// ---------------------------------------------------------------------------
__global__ __launch_bounds__(256) void partition_kernel(
    const int* __restrict__ e1, const int* __restrict__ e2,
    int* __restrict__ cursor, uint* __restrict__ slab)
{
    __shared__ int cnt[NBUCK2];
    __shared__ int basearr[NBUCK2];
    const int tid = threadIdx.x;
    for (int i = tid; i < NBUCK2; i += 256) cnt[i] = 0;
    __syncthreads();

    const int e0 = blockIdx.x * P1_CHUNK;
    uint ent[P1_PER_T];
    int  bkt[P1_PER_T];
    #pragma unroll
    for (int i = 0; i < P1_PER_T; ++i) {
        int e = e0 + i * 256 + tid;
        bkt[i] = -1;
        if (e < EN2) {
            int src, dst, lb;
            if (e < EN) {
                if (e < E_EDGES) { src = e1[e]; dst = e1[E_EDGES + e]; }
                else             { src = dst = e - E_EDGES; }
                lb = 0;
            } else {
                int f = e - EN;
                if (f < E_EDGES) { src = e2[f]; dst = e2[E_EDGES + f]; }
                else             { src = dst = f - E_EDGES; }
                lb = NBUCK_L;
            }
            bkt[i] = lb + (dst >> BSHIFT);
            ent[i] = (uint)src | ((uint)(dst & 511) << 17);
            atomicAdd(&cnt[bkt[i]], 1);
        }
    }
    __syncthreads();
    for (int b = tid; b < NBUCK2; b += 256) {
        int c = cnt[b];
        basearr[b] = (c > 0) ? atomicAdd(&cursor[b], c) : 0;
        cnt[b] = 0;                       // reuse as rank counter
    }
    __syncthreads();
    #pragma unroll
    for (int i = 0; i < P1_PER_T; ++i) {
        if (bkt[i] >= 0) {
            int r = basearr[bkt[i]] + atomicAdd(&cnt[bkt[i]], 1);
            if (r < CAP) slab[(long)bkt[i] * CAP + r] = ent[i];
        }
    }
}

// exclusive scan of the 392 bucket counts; single wave
__global__ void bucket_scan(const int* __restrict__ cursor, int* __restrict__ bbase)
{
    const int lane = threadIdx.x;     // 64 threads
    int v[7]; int s = 0;
    #pragma unroll
    for (int i = 0; i < 7; ++i) {
        int idx = lane * 7 + i;
        v[i] = (idx < NBUCK2) ? cursor[idx] : 0;
        s += v[i];
    }
    int incl = s;
    #pragma unroll
    for (int d = 1; d < 64; d <<= 1) {
        int t = __shfl_up(incl, d);
        if (lane >= d) incl += t;
    }
    int excl = incl - s;
    #pragma unroll
    for (int i = 0; i < 7; ++i) {
        int idx = lane * 7 + i;
        if (idx < NBUCK2) bbase[idx] = excl;
        excl += v[i];
    }
}

// ---------------------------------------------------------------------------
// CSR build, pass 2: one workgroup per bucket -> local CSR in LDS.
// ---------------------------------------------------------------------------
__global__ __launch_bounds__(256) void local_csr(
    const uint* __restrict__ slab, const int* __restrict__ cursor,
    const int* __restrict__ bbase, int* __restrict__ offs, int* __restrict__ esrc)
{
    __shared__ uint ent[CAP];         // 32 KB
    __shared__ int deg[512];
    __shared__ int excl[512];
    const int b = blockIdx.x;
    const int tid = threadIdx.x;
    const int cnt = min(cursor[b], CAP);
    const int base = bbase[b];
    const int layer = (b >= NBUCK_L);
    const int node0 = (b - layer * NBUCK_L) << BSHIFT;
    const int obase = layer * N_NODES;
    const int nodes_n = min(512, N_NODES - node0);

    for (int i = tid; i < 512; i += 256) deg[i] = 0;
    __syncthreads();
    for (int i = tid; i < cnt; i += 256) {
        uint v = slab[(long)b * CAP + i];
        ent[i] = v;
        atomicAdd(&deg[v >> 17], 1);
    }
    __syncthreads();
    if (tid < 64) {                   // wave-0 scan of deg[512], 8 per lane
        int v8[8]; int s = 0;
        #pragma unroll
        for (int i = 0; i < 8; ++i) { v8[i] = deg[tid * 8 + i]; s += v8[i]; }
        int incl = s;
        #pragma unroll
        for (int d = 1; d < 64; d <<= 1) {
            int t = __shfl_up(incl, d);
            if (tid >= d) incl += t;
        }
        int e = incl - s;
        #pragma unroll
        for (int i = 0; i < 8; ++i) { excl[tid * 8 + i] = e; e += v8[i]; }
    }
    __syncthreads();
    for (int i = tid; i < nodes_n; i += 256)
        offs[obase + node0 + i] = base + excl[i];
    for (int i = tid; i < 512; i += 256) deg[i] = 0;   // reuse as rank ctr
    if (tid == 0 && node0 + 512 >= N_NODES)
        offs[obase + N_NODES] = base + cnt;            // layer sentinel
    __syncthreads();
    for (int i = tid; i < cnt; i += 256) {
        uint v = ent[i];
        int dl = v >> 17;
        int r = atomicAdd(&deg[dl], 1);
        esrc[base + excl[dl] + r] = (int)(v & 0x1ffff);
    }
}

// ---------------------------------------------------------------------------
// Softmax aggregation, one wave per destination node.
// Lane mapping (r = lane>>4, c16 = lane&15): each lane loads a 16B chunk
// (8 bf16 channels) of edge-row jj+r -> 4 edges per load step, x2 unrolled
// (8 edges, 2 independent dwordx4 in flight) to break the latency chain.
// Out-of-range slots carry w=0 / src=0 (benign row-0 load, L2-hot).
// MODE 0: bf16 out, all nodes.  MODE 1: fp32 out, skip nodes with vflag==0.
// ---------------------------------------------------------------------------
template <int MODE>
__global__ __launch_bounds__(256) void aggregate(
    const ushort* __restrict__ hb, const float* __restrict__ a_s,
    const float* __restrict__ a_d, const float* __restrict__ bias,
    const int* __restrict__ offs, const int* __restrict__ esrc,
    const int* __restrict__ vflag, void* __restrict__ outp, int obase)
{
    const int wave = threadIdx.x >> 6;
    const int lane = threadIdx.x & 63;
    const int node = blockIdx.x * 4 + wave;   // grid*4 == N_NODES exactly
    if (MODE == 1 && vflag[node] == 0) return;

    const int r   = lane >> 4;
    const int c16 = lane & 15;
    const int start = offs[obase + node];
    const int end   = offs[obase + node + 1];
    const float ad  = a_d[node];

    float acc[8] = {0, 0, 0, 0, 0, 0, 0, 0};
    float dsum = 0.0f;

    for (int j0 = start; j0 < end; j0 += 64) {
        int j = j0 + lane;
        int cnt = min(64, end - j0);
        int s_l = 0;
        float w_l = 0.0f;
        if (j < end) {
            s_l = esrc[j];
            float e = a_s[s_l] + ad;
            e = (e >= 0.0f) ? e : 0.2f * e;
            w_l = __expf(e);
            dsum += w_l;
        }
        for (int jj = 0; jj < cnt; jj += 8) {
            int   i0 = jj + r,            i1 = jj + 4 + r;   // both <= 63 always
            float w0 = __shfl(w_l, i0);
            int   s0 = __shfl(s_l, i0);
            float w1 = __shfl(w_l, i1);
            int   s1 = __shfl(s_l, i1);
            const uint4 h0 = *reinterpret_cast<const uint4*>(hb + ((long)s0 << 7) + (c16 << 3));
            const uint4 h1 = *reinterpret_cast<const uint4*>(hb + ((long)s1 << 7) + (c16 << 3));
            acc[0] = fmaf(w0, __uint_as_float(h0.x << 16),          acc[0]);
            acc[1] = fmaf(w0, __uint_as_float(h0.x & 0xffff0000u),  acc[1]);
            acc[2] = fmaf(w0, __uint_as_float(h0.y << 16),          acc[2]);
            acc[3] = fmaf(w0, __uint_as_float(h0.y & 0xffff0000u),  acc[3]);
            acc[4] = fmaf(w0, __uint_as_float(h0.z << 16),          acc[4]);
            acc[5] = fmaf(w0, __uint_as_float(h0.z & 0xffff0000u),  acc[5]);
            acc[6] = fmaf(w0, __uint_as_float(h0.w << 16),          acc[6]);
            acc[7] = fmaf(w0, __uint_as_float(h0.w & 0xffff0000u),  acc[7]);
            acc[0] = fmaf(w1, __uint_as_float(h1.x << 16),          acc[0]);
            acc[1] = fmaf(w1, __uint_as_float(h1.x & 0xffff0000u),  acc[1]);
            acc[2] = fmaf(w1, __uint_as_float(h1.y << 16),          acc[2]);
            acc[3] = fmaf(w1, __uint_as_float(h1.y & 0xffff0000u),  acc[3]);
            acc[4] = fmaf(w1, __uint_as_float(h1.z << 16),          acc[4]);
            acc[5] = fmaf(w1, __uint_as_float(h1.z & 0xffff0000u),  acc[5]);
            acc[6] = fmaf(w1, __uint_as_float(h1.w << 16),          acc[6]);
            acc[7] = fmaf(w1, __uint_as_float(h1.w & 0xffff0000u),  acc[7]);
        }
    }
    #pragma unroll
    for (int d = 1; d < 64; d <<= 1) dsum += __shfl_xor(dsum, d);
    const float inv = 1.0f / (dsum + 1e-16f);

    #pragma unroll
    for (int k = 0; k < 8; ++k) {      // fold the 4 r-slices
        acc[k] += __shfl_xor(acc[k], 16);
        acc[k] += __shfl_xor(acc[k], 32);
    }

    if (r == 0) {
        const int c0 = c16 << 3;
        const float4 b0 = *reinterpret_cast<const float4*>(bias + c0);
        const float4 b1 = *reinterpret_cast<const float4*>(bias + c0 + 4);
        float res[8];
        res[0] = fmaf(acc[0], inv, b0.x);
        res[1] = fmaf(acc[1], inv, b0.y);
        res[2] = fmaf(acc[2], inv, b0.z);
        res[3] = fmaf(acc[3], inv, b0.w);
        res[4] = fmaf(acc[4], inv, b1.x);
        res[5] = fmaf(acc[5], inv, b1.y);
        res[6] = fmaf(acc[6], inv, b1.z);
        res[7] = fmaf(acc[7], inv, b1.w);
        if (MODE == 0) {
            uint4 pk;
            pk.x = (uint)f2bf(res[0]) | ((uint)f2bf(res[1]) << 16);
            pk.y = (uint)f2bf(res[2]) | ((uint)f2bf(res[3]) << 16);
            pk.z = (uint)f2bf(res[4]) | ((uint)f2bf(res[5]) << 16);
            pk.w = (uint)f2bf(res[6]) | ((uint)f2bf(res[7]) << 16);
            *reinterpret_cast<uint4*>((ushort*)outp + ((long)node << 7) + c0) = pk;
        } else {
            float* op = (float*)outp + ((long)node << 7) + c0;
            *reinterpret_cast<float4*>(op)     = make_float4(res[0], res[1], res[2], res[3]);
            *reinterpret_cast<float4*>(op + 4) = make_float4(res[4], res[5], res[6], res[7]);
        }
    }
}

__global__ void gather_out(const float* __restrict__ h, const int* __restrict__ idx,
                           float* __restrict__ out)
{
    int g = blockIdx.x * 256 + threadIdx.x;   // over V_OUT*32 float4s
    int v = g >> 5, c4 = (g & 31) << 2;
    long src = (long)idx[v] * C_DIM + c4;
    *reinterpret_cast<float4*>(out + ((long)v * C_DIM + c4)) =
        *reinterpret_cast<const float4*>(h + src);
}

// ---------------------------------------------------------------------------
extern "C" void kernel_launch(void* const* d_in, const int* in_sizes, int n_in,
                              void* d_out, int out_size, void* d_ws, size_t ws_size,
                              hipStream_t stream)
{
    const float* emb = (const float*)d_in[0];
    const float* W1  = (const float*)d_in[1];
    const float* as1 = (const float*)d_in[2];
    const float* ad1 = (const float*)d_in[3];
    const float* b1  = (const float*)d_in[4];
    const float* W2  = (const float*)d_in[5];
    const float* as2 = (const float*)d_in[6];
    const float* ad2 = (const float*)d_in[7];
    const float* b2  = (const float*)d_in[8];
    const int* edges1 = (const int*)d_in[9];
    const int* edges2 = (const int*)d_in[10];
    const int* idxm   = (const int*)d_in[11];
    float* out = (float*)d_out;

    char* p = (char*)d_ws;
    auto alloc = [&](size_t bytes) {
        char* r = p;
        p += (bytes + 255) & ~(size_t)255;
        return r;
    };
    float*  hB   = (float*)alloc((size_t)N_NODES * C_DIM * 4);   // 51.2 MB
    ushort* hb   = (ushort*)alloc((size_t)N_NODES * C_DIM * 2);  // 25.6 MB
    ushort* a1o  = (ushort*)alloc((size_t)N_NODES * C_DIM * 2);  // 25.6 MB
    uint*   slab = (uint*)alloc((size_t)NBUCK2 * CAP * 4);       // 12.9 MB
    int*    esrc = (int*)alloc((size_t)EN2 * 4);                 // 7.2 MB
    int*    offs = (int*)alloc((size_t)(M2 + 1) * 4);
    ushort* W1b  = (ushort*)alloc((size_t)C_DIM * C_DIM * 2);
    ushort* W2b  = (ushort*)alloc((size_t)C_DIM * C_DIM * 2);
    float*  aS   = (float*)alloc((size_t)N_NODES * 4);
    float*  aD   = (float*)alloc((size_t)N_NODES * 4);
    int*  cursor = (int*)alloc((size_t)NBUCK2 * 4);
    int*  bbase  = (int*)alloc((size_t)NBUCK2 * 4);
    int*  vflag  = (int*)alloc((size_t)N_NODES * 4);

    // ---- weight converts + vflag ----------------------------------------
    f2bf_kernel<<<(C_DIM * C_DIM / 4 + 255) / 256, 256, 0, stream>>>(W1, W1b, C_DIM * C_DIM / 4);
    f2bf_kernel<<<(C_DIM * C_DIM / 4 + 255) / 256, 256, 0, stream>>>(W2, W2b, C_DIM * C_DIM / 4);
    hipMemsetAsync(vflag, 0, (size_t)N_NODES * 4, stream);
    vflag_kernel<<<(V_OUT + 255) / 256, 256, 0, stream>>>(idxm, vflag);

    // ---- CSR build (both layers) -----------------------------------------
    hipMemsetAsync(cursor, 0, (size_t)NBUCK2 * 4, stream);
    partition_kernel<<<NCHUNK, 256, 0, stream>>>(edges1, edges2, cursor, slab);
    bucket_scan<<<1, 64, 0, stream>>>(cursor, bbase);
    local_csr<<<NBUCK2, 256, 0, stream>>>(slab, cursor, bbase, offs, esrc);

    // ---- layer 1 (fp32 emb read fused into gemm) -------------------------
    gemm_mfma<1><<<(N_NODES / 16 + 3) / 4, 256, 0, stream>>>(emb, W1b, as1, ad1, hb, aS, aD);
    aggregate<0><<<N_NODES / 4, 256, 0, stream>>>(hb, aS, aD, b1, offs, esrc, vflag, a1o, 0);

    // ---- layer 2 ---------------------------------------------------------
    gemm_mfma<0><<<(N_NODES / 16 + 3) / 4, 256, 0, stream>>>(a1o, W2b, as2, ad2, hb, aS, aD);
    aggregate<1><<<N_NODES / 4, 256, 0, stream>>>(hb, aS, aD, b2, offs, esrc, vflag, hB, N_NODES);

    // ---- final gather ----------------------------------------------------
    gather_out<<<(V_OUT * 32) / 256, 256, 0, stream>>>(hB, idxm, out);
}

// Round 5
// 311.929 us; speedup vs baseline: 1.9458x; 1.0014x over previous
//
#include <hip/hip_runtime.h>

#define N_NODES 100000
#define C_DIM 128
#define E_EDGES 800000
#define V_OUT 50000
#define EN (E_EDGES + N_NODES)      /* 900000  per-layer CSR entries */
#define M2 (2 * N_NODES)
#define EN2 (2 * EN)                /* 1800000 */

#define BSHIFT 9                    /* 512 nodes per coarse bucket */
#define NBUCK_L ((N_NODES + 511) >> 9)   /* 196 per layer */
#define NBUCK2 (2 * NBUCK_L)             /* 392 */
#define CAP 8192                    /* slab capacity; avg fill ~4608 */
#define P1_CHUNK 4096
#define P1_PER_T (P1_CHUNK / 256)   /* 16 */
#define NCHUNK ((EN2 + P1_CHUNK - 1) / P1_CHUNK) /* 440 */

#if defined(__has_builtin)
#if __has_builtin(__builtin_amdgcn_fdot2_f32_bf16) && __has_builtin(__builtin_amdgcn_perm)
#define HAS_DOT2 1
#endif
#endif

typedef unsigned int uint;
typedef unsigned short ushort;
typedef __attribute__((ext_vector_type(8))) short bf16x8;
typedef __attribute__((ext_vector_type(4))) float f32x4;
#ifdef HAS_DOT2
typedef __attribute__((ext_vector_type(2))) __bf16 bf16v2;
#endif

static __device__ __forceinline__ ushort f2bf(float f) {
    uint u = __float_as_uint(f);
    u += 0x7fffu + ((u >> 16) & 1);   // round-to-nearest-even
    return (ushort)(u >> 16);
}

// ---------------------------------------------------------------------------
// fp32 -> bf16 bulk convert (weights only)
// ---------------------------------------------------------------------------
__global__ void f2bf_kernel(const float* __restrict__ in, ushort* __restrict__ out, int n4)
{
    int i = blockIdx.x * 256 + threadIdx.x;
    if (i >= n4) return;
    float4 v = reinterpret_cast<const float4*>(in)[i];
    ushort4 r;
    r.x = f2bf(v.x); r.y = f2bf(v.y); r.z = f2bf(v.z); r.w = f2bf(v.w);
    reinterpret_cast<ushort4*>(out)[i] = r;
}

// mark nodes that appear in idx_mapping (races benign: all write 1)
__global__ void vflag_kernel(const int* __restrict__ idx, int* __restrict__ vflag)
{
    int v = blockIdx.x * 256 + threadIdx.x;
    if (v < V_OUT) vflag[idx[v]] = 1;
}

// ---------------------------------------------------------------------------
// MFMA GEMM: h[n,c] = sum_k x[n,k] * W[c,k] (bf16/fp32 in, fp32 acc, bf16 out)
// + fused scores a_s = h.att_src, a_d = h.att_dst.
// A frag: A[m=lane&15][k=quad*8+j]; B mirrored; D: col=lane&15, row=quad*4+r.
// ---------------------------------------------------------------------------
template <int IN_F32>
__global__ __launch_bounds__(256) void gemm_mfma(
    const void* __restrict__ xin, const ushort* __restrict__ Wb,
    const float* __restrict__ att_s, const float* __restrict__ att_d,
    ushort* __restrict__ hb, float* __restrict__ a_s, float* __restrict__ a_d)
{
    const int lane = threadIdx.x & 63;
    const int wv   = threadIdx.x >> 6;
    const int nb   = (blockIdx.x * 4 + wv) * 16;
    if (nb >= N_NODES) return;
    const int m    = lane & 15;
    const int quad = lane >> 4;

    bf16x8 a[4];
    if (IN_F32) {
        const float* xrow = (const float*)xin + (long)(nb + m) * 128 + quad * 8;
        #pragma unroll
        for (int ki = 0; ki < 4; ++ki) {
            float4 u = *reinterpret_cast<const float4*>(xrow + ki * 32);
            float4 v = *reinterpret_cast<const float4*>(xrow + ki * 32 + 4);
            bf16x8 t;
            t[0] = (short)f2bf(u.x); t[1] = (short)f2bf(u.y);
            t[2] = (short)f2bf(u.z); t[3] = (short)f2bf(u.w);
            t[4] = (short)f2bf(v.x); t[5] = (short)f2bf(v.y);
            t[6] = (short)f2bf(v.z); t[7] = (short)f2bf(v.w);
            a[ki] = t;
        }
    } else {
        const ushort* xrow = (const ushort*)xin + (long)(nb + m) * 128 + quad * 8;
        #pragma unroll
        for (int ki = 0; ki < 4; ++ki)
            a[ki] = *reinterpret_cast<const bf16x8*>(xrow + ki * 32);
    }

    float ps[4] = {0, 0, 0, 0}, pd[4] = {0, 0, 0, 0};

    #pragma unroll
    for (int ct = 0; ct < 8; ++ct) {
        const int c = ct * 16 + m;
        const ushort* wrow = Wb + (long)c * 128 + quad * 8;
        f32x4 acc = {0.f, 0.f, 0.f, 0.f};
        #pragma unroll
        for (int ki = 0; ki < 4; ++ki) {
            bf16x8 b = *reinterpret_cast<const bf16x8*>(wrow + ki * 32);
            acc = __builtin_amdgcn_mfma_f32_16x16x32_bf16(a[ki], b, acc, 0, 0, 0);
        }
        const float asc = att_s[c], adc = att_d[c];
        #pragma unroll
        for (int r = 0; r < 4; ++r) {
            const int node = nb + quad * 4 + r;
            hb[(long)node * 128 + c] = f2bf(acc[r]);
            ps[r] = fmaf(acc[r], asc, ps[r]);
            pd[r] = fmaf(acc[r], adc, pd[r]);
        }
    }
    #pragma unroll
    for (int r = 0; r < 4; ++r) {
        float s = ps[r], d = pd[r];
        #pragma unroll
        for (int x = 1; x < 16; x <<= 1) { s += __shfl_xor(s, x); d += __shfl_xor(d, x); }
        if (m == 0) {
            const int node = nb + quad * 4 + r;
            a_s[node] = s; a_d[node] = d;
        }
    }
}

// ---------------------------------------------------------------------------
// CSR build, pass 1: partition edges into 392 coarse buckets of 512 dst.
// ---------------------------------------------------------------------------
__global__ __launch_bounds__(256) void partition_kernel(
    const int* __restrict__ e1, const int* __restrict__ e2,
    int* __restrict__ cursor, uint* __restrict__ slab)
{
    __shared__ int cnt[NBUCK2];
    __shared__ int basearr[NBUCK2];
    const int tid = threadIdx.x;
    for (int i = tid; i < NBUCK2; i += 256) cnt[i] = 0;
    __syncthreads();

    const int e0 = blockIdx.x * P1_CHUNK;
    uint ent[P1_PER_T];
    int  bkt[P1_PER_T];
    #pragma unroll
    for (int i = 0; i < P1_PER_T; ++i) {
        int e = e0 + i * 256 + tid;
        bkt[i] = -1;
        if (e < EN2) {
            int src, dst, lb;
            if (e < EN) {
                if (e < E_EDGES) { src = e1[e]; dst = e1[E_EDGES + e]; }
                else             { src = dst = e - E_EDGES; }
                lb = 0;
            } else {
                int f = e - EN;
                if (f < E_EDGES) { src = e2[f]; dst = e2[E_EDGES + f]; }
                else             { src = dst = f - E_EDGES; }
                lb = NBUCK_L;
            }
            bkt[i] = lb + (dst >> BSHIFT);
            ent[i] = (uint)src | ((uint)(dst & 511) << 17);
            atomicAdd(&cnt[bkt[i]], 1);
        }
    }
    __syncthreads();
    for (int b = tid; b < NBUCK2; b += 256) {
        int c = cnt[b];
        basearr[b] = (c > 0) ? atomicAdd(&cursor[b], c) : 0;
        cnt[b] = 0;                       // reuse as rank counter
    }
    __syncthreads();
    #pragma unroll
    for (int i = 0; i < P1_PER_T; ++i) {
        if (bkt[i] >= 0) {
            int r = basearr[bkt[i]] + atomicAdd(&cnt[bkt[i]], 1);
            if (r < CAP) slab[(long)bkt[i] * CAP + r] = ent[i];
        }
    }
}

// exclusive scan of the 392 bucket counts; single wave
__global__ void bucket_scan(const int* __restrict__ cursor, int* __restrict__ bbase)
{
    const int lane = threadIdx.x;     // 64 threads
    int v[7]; int s = 0;
    #pragma unroll
    for (int i = 0; i < 7; ++i) {
        int idx = lane * 7 + i;
        v[i] = (idx < NBUCK2) ? cursor[idx] : 0;
        s += v[i];
    }
    int incl = s;
    #pragma unroll
    for (int d = 1; d < 64; d <<= 1) {
        int t = __shfl_up(incl, d);
        if (lane >= d) incl += t;
    }
    int excl = incl - s;
    #pragma unroll
    for (int i = 0; i < 7; ++i) {
        int idx = lane * 7 + i;
        if (idx < NBUCK2) bbase[idx] = excl;
        excl += v[i];
    }
}

// ---------------------------------------------------------------------------
// CSR build, pass 2: one workgroup per bucket -> local CSR in LDS.
// ---------------------------------------------------------------------------
__global__ __launch_bounds__(256) void local_csr(
    const uint* __restrict__ slab, const int* __restrict__ cursor,
    const int* __restrict__ bbase, int* __restrict__ offs, int* __restrict__ esrc)
{
    __shared__ uint ent[CAP];         // 32 KB
    __shared__ int deg[512];
    __shared__ int excl[512];
    const int b = blockIdx.x;
    const int tid = threadIdx.x;
    const int cnt = min(cursor[b], CAP);
    const int base = bbase[b];
    const int layer = (b >= NBUCK_L);
    const int node0 = (b - layer * NBUCK_L) << BSHIFT;
    const int obase = layer * N_NODES;
    const int nodes_n = min(512, N_NODES - node0);

    for (int i = tid; i < 512; i += 256) deg[i] = 0;
    __syncthreads();
    for (int i = tid; i < cnt; i += 256) {
        uint v = slab[(long)b * CAP + i];
        ent[i] = v;
        atomicAdd(&deg[v >> 17], 1);
    }
    __syncthreads();
    if (tid < 64) {                   // wave-0 scan of deg[512], 8 per lane
        int v8[8]; int s = 0;
        #pragma unroll
        for (int i = 0; i < 8; ++i) { v8[i] = deg[tid * 8 + i]; s += v8[i]; }
        int incl = s;
        #pragma unroll
        for (int d = 1; d < 64; d <<= 1) {
            int t = __shfl_up(incl, d);
            if (tid >= d) incl += t;
        }
        int e = incl - s;
        #pragma unroll
        for (int i = 0; i < 8; ++i) { excl[tid * 8 + i] = e; e += v8[i]; }
    }
    __syncthreads();
    for (int i = tid; i < nodes_n; i += 256)
        offs[obase + node0 + i] = base + excl[i];
    for (int i = tid; i < 512; i += 256) deg[i] = 0;   // reuse as rank ctr
    if (tid == 0 && node0 + 512 >= N_NODES)
        offs[obase + N_NODES] = base + cnt;            // layer sentinel
    __syncthreads();
    for (int i = tid; i < cnt; i += 256) {
        uint v = ent[i];
        int dl = v >> 17;
        int r = atomicAdd(&deg[dl], 1);
        esrc[base + excl[dl] + r] = (int)(v & 0x1ffff);
    }
}

// ---------------------------------------------------------------------------
// Softmax aggregation, one wave per destination node.
// Edge PAIRS: lane p<32 holds pack (w_{2p}, w_{2p+1}) as bf16x2 + both srcs.
// Inner iteration: r = lane>>4 covers pairs pp+r and pp+4+r -> 16 edges,
// 4 independent dwordx4 row loads in flight per lane. Per uint (2ch x 2edges):
// 2 v_perm_b32 + 2 v_dot2_f32_bf16 (vs 4 unpack + 4 fma) -> ~halved VALU.
// Out-of-range pairs carry w=0 / src=0 (benign row-0 load, cache-hot).
// MODE 0: bf16 out, all nodes.  MODE 1: fp32 out, skip nodes with vflag==0.
// ---------------------------------------------------------------------------
template <int MODE>
__global__ __launch_bounds__(256) void aggregate(
    const ushort* __restrict__ hb, const float* __restrict__ a_s,
    const float* __restrict__ a_d, const float* __restrict__ bias,
    const int* __restrict__ offs, const int* __restrict__ esrc,
    const int* __restrict__ vflag, void* __restrict__ outp, int obase)
{
    const int wave = threadIdx.x >> 6;
    const int lane = threadIdx.x & 63;
    const int node = blockIdx.x * 4 + wave;   // grid*4 == N_NODES exactly
    if (MODE == 1 && vflag[node] == 0) return;

    const int r   = lane >> 4;
    const int c16 = lane & 15;
    const int start = offs[obase + node];
    const int end   = offs[obase + node + 1];
    const float ad  = a_d[node];

    float acc[8] = {0, 0, 0, 0, 0, 0, 0, 0};
    float dsum = 0.0f;

    for (int j0 = start; j0 < end; j0 += 64) {
        int j = j0 + lane;
        int cnt = min(64, end - j0);
        int s_l = 0;
        float w_l = 0.0f;
        if (j < end) {
            s_l = esrc[j];
            float e = a_s[s_l] + ad;
            e = (e >= 0.0f) ? e : 0.2f * e;
            w_l = __expf(e);
            dsum += w_l;
        }
        // pair packing: lane p holds weights/srcs of edges (2p, 2p+1)
        float wA = __shfl(w_l, (lane * 2) & 63);
        float wB = __shfl(w_l, (lane * 2 + 1) & 63);
        int   sA = __shfl(s_l, (lane * 2) & 63);
        int   sB = __shfl(s_l, (lane * 2 + 1) & 63);
        if (lane >= 32) { wA = 0.0f; wB = 0.0f; sA = 0; sB = 0; }
#ifdef HAS_DOT2
        uint wpk = (uint)f2bf(wA) | ((uint)f2bf(wB) << 16);
#endif
        const int npairs = (cnt + 1) >> 1;
        for (int pp = 0; pp < npairs; pp += 8) {
            const int p0 = pp + r, p1 = pp + 4 + r;   // <= 35 < 64 always
            int e0A = __shfl(sA, p0), e0B = __shfl(sB, p0);
            int e1A = __shfl(sA, p1), e1B = __shfl(sB, p1);
            const uint4 h0A = *reinterpret_cast<const uint4*>(hb + ((long)e0A << 7) + (c16 << 3));
            const uint4 h0B = *reinterpret_cast<const uint4*>(hb + ((long)e0B << 7) + (c16 << 3));
            const uint4 h1A = *reinterpret_cast<const uint4*>(hb + ((long)e1A << 7) + (c16 << 3));
            const uint4 h1B = *reinterpret_cast<const uint4*>(hb + ((long)e1B << 7) + (c16 << 3));
#ifdef HAS_DOT2
            uint q0 = __shfl(wpk, p0);
            uint q1 = __shfl(wpk, p1);
            bf16v2 q0v = __builtin_bit_cast(bf16v2, q0);
            bf16v2 q1v = __builtin_bit_cast(bf16v2, q1);
            #define DOT_STEP(aw, bw, qv, k)                                              \
            {                                                                            \
                uint lo = __builtin_amdgcn_perm((bw), (aw), 0x05040100u);                \
                uint hi = __builtin_amdgcn_perm((bw), (aw), 0x07060302u);                \
                acc[2*(k)]   = __builtin_amdgcn_fdot2_f32_bf16(                          \
                                   __builtin_bit_cast(bf16v2, lo), (qv), acc[2*(k)], false); \
                acc[2*(k)+1] = __builtin_amdgcn_fdot2_f32_bf16(                          \
                                   __builtin_bit_cast(bf16v2, hi), (qv), acc[2*(k)+1], false); \
            }
            DOT_STEP(h0A.x, h0B.x, q0v, 0)
            DOT_STEP(h0A.y, h0B.y, q0v, 1)
            DOT_STEP(h0A.z, h0B.z, q0v, 2)
            DOT_STEP(h0A.w, h0B.w, q0v, 3)
            DOT_STEP(h1A.x, h1B.x, q1v, 0)
            DOT_STEP(h1A.y, h1B.y, q1v, 1)
            DOT_STEP(h1A.z, h1B.z, q1v, 2)
            DOT_STEP(h1A.w, h1B.w, q1v, 3)
            #undef DOT_STEP
#else
            float w0A = __shfl(wA, p0), w0B = __shfl(wB, p0);
            float w1A = __shfl(wA, p1), w1B = __shfl(wB, p1);
            #define FMA_STEP(word, wgt, k)                                               \
            {                                                                            \
                acc[2*(k)]   = fmaf((wgt), __uint_as_float((word) << 16),         acc[2*(k)]);   \
                acc[2*(k)+1] = fmaf((wgt), __uint_as_float((word) & 0xffff0000u), acc[2*(k)+1]); \
            }
            FMA_STEP(h0A.x, w0A, 0) FMA_STEP(h0A.y, w0A, 1)
            FMA_STEP(h0A.z, w0A, 2) FMA_STEP(h0A.w, w0A, 3)
            FMA_STEP(h0B.x, w0B, 0) FMA_STEP(h0B.y, w0B, 1)
            FMA_STEP(h0B.z, w0B, 2) FMA_STEP(h0B.w, w0B, 3)
            FMA_STEP(h1A.x, w1A, 0) FMA_STEP(h1A.y, w1A, 1)
            FMA_STEP(h1A.z, w1A, 2) FMA_STEP(h1A.w, w1A, 3)
            FMA_STEP(h1B.x, w1B, 0) FMA_STEP(h1B.y, w1B, 1)
            FMA_STEP(h1B.z, w1B, 2) FMA_STEP(h1B.w, w1B, 3)
            #undef FMA_STEP
#endif
        }
    }
    #pragma unroll
    for (int d = 1; d < 64; d <<= 1) dsum += __shfl_xor(dsum, d);
    const float inv = 1.0f / (dsum + 1e-16f);

    #pragma unroll
    for (int k = 0; k < 8; ++k) {      // fold the 4 r-slices
        acc[k] += __shfl_xor(acc[k], 16);
        acc[k] += __shfl_xor(acc[k], 32);
    }

    if (r == 0) {
        const int c0 = c16 << 3;
        const float4 b0 = *reinterpret_cast<const float4*>(bias + c0);
        const float4 b1 = *reinterpret_cast<const float4*>(bias + c0 + 4);
        float res[8];
        res[0] = fmaf(acc[0], inv, b0.x);
        res[1] = fmaf(acc[1], inv, b0.y);
        res[2] = fmaf(acc[2], inv, b0.z);
        res[3] = fmaf(acc[3], inv, b0.w);
        res[4] = fmaf(acc[4], inv, b1.x);
        res[5] = fmaf(acc[5], inv, b1.y);
        res[6] = fmaf(acc[6], inv, b1.z);
        res[7] = fmaf(acc[7], inv, b1.w);
        if (MODE == 0) {
            uint4 pk;
            pk.x = (uint)f2bf(res[0]) | ((uint)f2bf(res[1]) << 16);
            pk.y = (uint)f2bf(res[2]) | ((uint)f2bf(res[3]) << 16);
            pk.z = (uint)f2bf(res[4]) | ((uint)f2bf(res[5]) << 16);
            pk.w = (uint)f2bf(res[6]) | ((uint)f2bf(res[7]) << 16);
            *reinterpret_cast<uint4*>((ushort*)outp + ((long)node << 7) + c0) = pk;
        } else {
            float* op = (float*)outp + ((long)node << 7) + c0;
            *reinterpret_cast<float4*>(op)     = make_float4(res[0], res[1], res[2], res[3]);
            *reinterpret_cast<float4*>(op + 4) = make_float4(res[4], res[5], res[6], res[7]);
        }
    }
}

__global__ void gather_out(const float* __restrict__ h, const int* __restrict__ idx,
                           float* __restrict__ out)
{
    int g = blockIdx.x * 256 + threadIdx.x;   // over V_OUT*32 float4s
    int v = g >> 5, c4 = (g & 31) << 2;
    long src = (long)idx[v] * C_DIM + c4;
    *reinterpret_cast<float4*>(out + ((long)v * C_DIM + c4)) =
        *reinterpret_cast<const float4*>(h + src);
}

// ---------------------------------------------------------------------------
extern "C" void kernel_launch(void* const* d_in, const int* in_sizes, int n_in,
                              void* d_out, int out_size, void* d_ws, size_t ws_size,
                              hipStream_t stream)
{
    const float* emb = (const float*)d_in[0];
    const float* W1  = (const float*)d_in[1];
    const float* as1 = (const float*)d_in[2];
    const float* ad1 = (const float*)d_in[3];
    const float* b1  = (const float*)d_in[4];
    const float* W2  = (const float*)d_in[5];
    const float* as2 = (const float*)d_in[6];
    const float* ad2 = (const float*)d_in[7];
    const float* b2  = (const float*)d_in[8];
    const int* edges1 = (const int*)d_in[9];
    const int* edges2 = (const int*)d_in[10];
    const int* idxm   = (const int*)d_in[11];
    float* out = (float*)d_out;

    char* p = (char*)d_ws;
    auto alloc = [&](size_t bytes) {
        char* r = p;
        p += (bytes + 255) & ~(size_t)255;
        return r;
    };
    float*  hB   = (float*)alloc((size_t)N_NODES * C_DIM * 4);   // 51.2 MB
    ushort* hb   = (ushort*)alloc((size_t)N_NODES * C_DIM * 2);  // 25.6 MB
    ushort* a1o  = (ushort*)alloc((size_t)N_NODES * C_DIM * 2);  // 25.6 MB
    uint*   slab = (uint*)alloc((size_t)NBUCK2 * CAP * 4);       // 12.9 MB
    int*    esrc = (int*)alloc((size_t)EN2 * 4);                 // 7.2 MB
    int*    offs = (int*)alloc((size_t)(M2 + 1) * 4);
    ushort* W1b  = (ushort*)alloc((size_t)C_DIM * C_DIM * 2);
    ushort* W2b  = (ushort*)alloc((size_t)C_DIM * C_DIM * 2);
    float*  aS   = (float*)alloc((size_t)N_NODES * 4);
    float*  aD   = (float*)alloc((size_t)N_NODES * 4);
    int*  bbase  = (int*)alloc((size_t)NBUCK2 * 4);
    // cursor + vflag contiguous -> one memset covers both
    int*  cursor = (int*)alloc((size_t)NBUCK2 * 4);
    int*  vflag  = (int*)alloc((size_t)N_NODES * 4);

    // ---- zero cursor+vflag in one memset, weight converts, vflag ---------
    hipMemsetAsync(cursor, 0, (size_t)((char*)vflag - (char*)cursor) + (size_t)N_NODES * 4, stream);
    f2bf_kernel<<<(C_DIM * C_DIM / 4 + 255) / 256, 256, 0, stream>>>(W1, W1b, C_DIM * C_DIM / 4);
    f2bf_kernel<<<(C_DIM * C_DIM / 4 + 255) / 256, 256, 0, stream>>>(W2, W2b, C_DIM * C_DIM / 4);
    vflag_kernel<<<(V_OUT + 255) / 256, 256, 0, stream>>>(idxm, vflag);

    // ---- CSR build (both layers) -----------------------------------------
    partition_kernel<<<NCHUNK, 256, 0, stream>>>(edges1, edges2, cursor, slab);
    bucket_scan<<<1, 64, 0, stream>>>(cursor, bbase);
    local_csr<<<NBUCK2, 256, 0, stream>>>(slab, cursor, bbase, offs, esrc);

    // ---- layer 1 (fp32 emb read fused into gemm) -------------------------
    gemm_mfma<1><<<(N_NODES / 16 + 3) / 4, 256, 0, stream>>>(emb, W1b, as1, ad1, hb, aS, aD);
    aggregate<0><<<N_NODES / 4, 256, 0, stream>>>(hb, aS, aD, b1, offs, esrc, vflag, a1o, 0);

    // ---- layer 2 ---------------------------------------------------------
    gemm_mfma<0><<<(N_NODES / 16 + 3) / 4, 256, 0, stream>>>(a1o, W2b, as2, ad2, hb, aS, aD);
    aggregate<1><<<N_NODES / 4, 256, 0, stream>>>(hb, aS, aD, b2, offs, esrc, vflag, hB, N_NODES);

    // ---- final gather ----------------------------------------------------
    gather_out<<<(V_OUT * 32) / 256, 256, 0, stream>>>(hB, idxm, out);
}